// Round 2
// baseline (327.212 us; speedup 1.0000x reference)
//
#include <hip/hip_runtime.h>

// Unfold: x (B=16, C=128, H=64, W=64) f32 -> y (B, C*9, H*W) f32
// y[bc, t, h*W+w] = x[bc, h+dh, w+dw] (zero-padded), t = (dh+1)*3 + (dw+1)
//
// R2: LDS-free, register-direct scheme.
//   - Each thread loads 4 aligned f32x4 chunks of its plane (rows h = q*16 + j/16,
//     cols 4*(j%16)..+3). Plane read from HBM exactly once, coalesced.
//   - Vertical shifts (dh) are pure address re-indexing: data for output row r of
//     copy t is input row r+dh, so the OWNER of input row h stores it at row h-dh.
//     Threads whose target row is out of range write the zero-row instead
//     (dh=+1 -> y row 63 is zeros; dh=-1 -> y row 0). Exactly 36 stores/thread,
//     every output byte written exactly once.
//   - Horizontal shifts (dw=+-1) via two width-16 shuffles per chunk:
//     sR = [v.y, v.z, v.w, next_lane.v.x]  (y[w] = x[w+1]), lane15 tail = 0
//     sL = [prev_lane.v.w, v.x, v.y, v.z]  (y[w] = x[w-1]), lane0 head  = 0
//     The zeroed lane edges ARE the zero-padding columns -> all stores remain
//     16B-aligned, wave-contiguous 1 KB spans, no partial/edge stores.
//   - No __shared__, no barrier, no lgkmcnt in the store loop: all 36 stores are
//     register-sourced and independent -> stores stream at L2/HBM acceptance
//     rate like the 6.35 TB/s fill kernel, instead of stalling on ds_read chains.
//
// Traffic: 33.5 MB read + 302 MB write -> ~53 us floor at 6.3 TB/s.

typedef float f32x4 __attribute__((ext_vector_type(4)));

__global__ __launch_bounds__(256) void unfold_kernel(
    const float* __restrict__ x, float* __restrict__ y) {
    const int j      = threadIdx.x;
    const int bc     = blockIdx.x;
    const int lane16 = j & 15;   // column-group within row: cols 4*lane16 .. +3
    const int rowid  = j >> 4;   // row within 16-row band

    // 1) Load the whole plane into registers (4 x 16 B per thread, coalesced).
    const f32x4* plane = (const f32x4*)(x + ((size_t)bc << 12));
    f32x4 v[4];
    #pragma unroll
    for (int q = 0; q < 4; ++q) v[q] = plane[q * 256 + j];

    // 2) Build horizontally-shifted vectors with width-16 shuffles.
    //    Lane-group edges forced to 0 == the zero-pad columns.
    f32x4 sL[4], sR[4];
    #pragma unroll
    for (int q = 0; q < 4; ++q) {
        float nxt = __shfl_down(v[q].x, 1, 16);  // x[c+4] from lane+1 (same row)
        float prv = __shfl_up  (v[q].w, 1, 16);  // x[c-1] from lane-1 (same row)
        nxt = (lane16 == 15) ? 0.f : nxt;
        prv = (lane16 == 0)  ? 0.f : prv;
        sR[q].x = v[q].y; sR[q].y = v[q].z; sR[q].z = v[q].w; sR[q].w = nxt;
        sL[q].x = prv;    sL[q].y = v[q].x; sL[q].z = v[q].y; sL[q].w = v[q].z;
    }

    const f32x4 zero4 = {0.f, 0.f, 0.f, 0.f};

    // 3) 9 shifted copies, all register-sourced, all independent stores.
    float* ybase = y + ((size_t)bc * 9 << 12);
    #pragma unroll
    for (int t = 0; t < 9; ++t) {
        const int dh = t / 3 - 1;
        const int dw = t % 3 - 1;
        f32x4* yt = (f32x4*)(ybase + ((size_t)t << 12));
        #pragma unroll
        for (int q = 0; q < 4; ++q) {
            const int h    = (q << 4) + rowid;       // input row this chunk holds
            const int orow = h - dh;                 // its target output row
            const bool valid = ((unsigned)orow) < 64u;
            f32x4 sv = (dw == 0) ? v[q] : ((dw > 0) ? sR[q] : sL[q]);
            // Out-of-range owners (only h==0 for dh=+1, h==63 for dh=-1)
            // write the zero-row of this copy instead.
            f32x4 out = sv;
            int   row = orow;
            if (!valid) { out = zero4; row = (dh > 0) ? 63 : 0; }
            yt[(row << 4) + lane16] = out;
        }
    }
}

extern "C" void kernel_launch(void* const* d_in, const int* in_sizes, int n_in,
                              void* d_out, int out_size, void* d_ws, size_t ws_size,
                              hipStream_t stream) {
    const float* x = (const float*)d_in[0];
    // d_in[1] is the fixed identity eye(9) kernel -- effect hard-coded.
    float* y = (float*)d_out;

    // B*C = 2048 planes -> 2048 blocks.
    unfold_kernel<<<2048, 256, 0, stream>>>(x, y);
}